// Round 2
// baseline (495.621 us; speedup 1.0000x reference)
//
#include <hip/hip_runtime.h>
#include <hip/hip_bf16.h>
#include <stdint.h>

#define BN 16
#define SN 2048
#define DN 128
#define SCALE 0.08838834764831845f   // 1/sqrt(128)

typedef float  f32x4  __attribute__((ext_vector_type(4)));
typedef short  s16x8  __attribute__((ext_vector_type(8)));
typedef short  s16x4  __attribute__((ext_vector_type(4)));
typedef __bf16 bf16x8 __attribute__((ext_vector_type(8)));

static __device__ __forceinline__ bf16x8 as_bf(s16x8 v) {
    return __builtin_bit_cast(bf16x8, v);
}
static __device__ __forceinline__ short f2bf(float f) {
    return __builtin_bit_cast(short, (__bf16)f);
}
static __device__ __forceinline__ short f2h(float f) {
    return __builtin_bit_cast(short, (_Float16)f);
}
static __device__ __forceinline__ float h2f(short s) {
    return (float)__builtin_bit_cast(_Float16, s);
}

// ---------------------------------------------------------------- prep: cast
__global__ void cast_bf16_kernel(const float* __restrict__ src,
                                 short* __restrict__ dst, int n4) {
    int idx = blockIdx.x * blockDim.x + threadIdx.x;
    if (idx >= n4) return;
    const float4 v = ((const float4*)src)[idx];
    s16x4 o;
    o[0] = f2bf(v.x); o[1] = f2bf(v.y); o[2] = f2bf(v.z); o[3] = f2bf(v.w);
    ((s16x4*)dst)[idx] = o;
}

// ------------------------------------------------- prep: V -> V^T (bf16)
__global__ void transpose_v_kernel(const float* __restrict__ V,
                                   short* __restrict__ Vt) {
    __shared__ float tile[64][65];
    const int b = blockIdx.z, j0 = blockIdx.x * 64, d0 = blockIdx.y * 64;
    const int t = threadIdx.x;
    const int r = t >> 4, c4 = (t & 15) * 4;
    const float* src = V + ((size_t)b * SN + j0) * DN + d0;
    for (int it = 0; it < 4; ++it) {
        int rr = r + it * 16;
        const float4 v = *(const float4*)(src + (size_t)rr * DN + c4);
        tile[rr][c4 + 0] = v.x; tile[rr][c4 + 1] = v.y;
        tile[rr][c4 + 2] = v.z; tile[rr][c4 + 3] = v.w;
    }
    __syncthreads();
    short* dst = Vt + ((size_t)b * DN + d0) * SN + j0;
    for (int it = 0; it < 4; ++it) {
        int dr = r + it * 16;
        s16x4 o;
        o[0] = f2bf(tile[c4 + 0][dr]);
        o[1] = f2bf(tile[c4 + 1][dr]);
        o[2] = f2bf(tile[c4 + 2][dr]);
        o[3] = f2bf(tile[c4 + 3][dr]);
        *(s16x4*)(dst + (size_t)dr * SN + c4) = o;
    }
}

// ------------------------------------------------------------- attention
// Single-pass flash: QK^T once per tile, raw scores -> f16 blob (coalesced,
// MFMA register order), online (m,l) with O rescale, PV unnormalized.
__launch_bounds__(256, 2)
__global__ void attn_kernel(const short* __restrict__ Qb,
                            const short* __restrict__ Kb,
                            const short* __restrict__ Vtb,
                            float* __restrict__ O,
                            short* __restrict__ blob,
                            float* __restrict__ Mr,
                            float* __restrict__ Rr) {
    __shared__ short Ks[64 * 136];   // K tile [j][d], pad 8
    __shared__ short Vs[128 * 72];   // V^T tile [d][j], pad 8
    __shared__ short Ps[64 * 72];    // P tile [i][j], pad 8

    const int tid  = threadIdx.x;
    const int wave = tid >> 6;
    const int lane = tid & 63;
    const int l15  = lane & 15;
    const int quad = lane >> 4;

    // pair block n with n+256 so per-CU causal work is ~constant
    const int idx  = blockIdx.x;
    const int half = idx >> 8;
    const int rr_  = idx & 255;
    const int b    = ((rr_ >> 5) << 1) | half;
    const int qr   = rr_ & 31;
    const int qt   = half ? (31 - qr) : qr;
    const int i0   = qt * 64;
    const int ntiles = qt + 1;

    bf16x8 qf[4];
    {
        const short* qp = Qb + ((size_t)b * SN + (i0 + wave * 16 + l15)) * DN + quad * 8;
        for (int ks = 0; ks < 4; ++ks)
            qf[ks] = as_bf(*(const s16x8*)(qp + ks * 32));
    }

    float m_[4], l_[4];
    for (int g = 0; g < 4; ++g) { m_[g] = -1e30f; l_[g] = 0.f; }

    f32x4 oacc[8];
    const f32x4 zero4 = {0.f, 0.f, 0.f, 0.f};
    for (int nt = 0; nt < 8; ++nt) oacc[nt] = zero4;

    const short* kbase = Kb  + (size_t)b * SN * DN;
    const short* vbase = Vtb + (size_t)b * DN * SN;
    const size_t tri   = (size_t)qt * (qt + 1) / 2;
    short* bbase = blob + ((size_t)b * 528 + tri) * 4096 + wave * 512 + lane * 8;

    for (int tI = 0; tI < ntiles; ++tI) {
        const int j0 = tI * 64;
        __syncthreads();
        {   // stage K tile + V^T tile
            const int row = tid >> 4, d0 = (tid & 15) * 8;
            for (int it = 0; it < 4; ++it) {
                int rj = row + it * 16;
                *(s16x8*)(Ks + rj * 136 + d0) =
                    *(const s16x8*)(kbase + (size_t)(j0 + rj) * DN + d0);
            }
            const int dd = tid >> 3, jj0 = (tid & 7) * 8;
            for (int it = 0; it < 4; ++it) {
                int dr = dd + it * 32;
                *(s16x8*)(Vs + dr * 72 + jj0) =
                    *(const s16x8*)(vbase + (size_t)dr * SN + j0 + jj0);
            }
        }
        __syncthreads();

        // QK^T (one pass)
        f32x4 sacc[4];
        for (int ct = 0; ct < 4; ++ct) {
            f32x4 c = {0.f, 0.f, 0.f, 0.f};
            const short* kp = Ks + (ct * 16 + l15) * 136 + quad * 8;
            for (int ks = 0; ks < 4; ++ks)
                c = __builtin_amdgcn_mfma_f32_16x16x32_bf16(
                        qf[ks], as_bf(*(const s16x8*)(kp + ks * 32)), c, 0, 0, 0);
            sacc[ct] = c * SCALE;
        }
        if (j0 == i0) {  // straddle tile: mask j > i
            for (int ct = 0; ct < 4; ++ct)
                for (int g = 0; g < 4; ++g) {
                    int i = i0 + wave * 16 + quad * 4 + g;
                    int j = j0 + ct * 16 + l15;
                    if (j > i) sacc[ct][g] = -1e30f;
                }
        }

        // raw score dump: f16, register order, 2x16B coalesced stores
        {
            s16x8 h0, h1;
            for (int ct = 0; ct < 4; ++ct)
                for (int g = 0; g < 4; ++g) {
                    int e = ct * 4 + g;
                    short hv = f2h(sacc[ct][g]);
                    if (e < 8) h0[e] = hv; else h1[e - 8] = hv;
                }
            short* bt = bbase + (size_t)tI * 4096;
            *(s16x8*)(bt)        = h0;
            *(s16x8*)(bt + 2048) = h1;
        }

        // online softmax update + P (unnormalized) -> LDS
        for (int g = 0; g < 4; ++g) {
            float tm = fmaxf(fmaxf(sacc[0][g], sacc[1][g]),
                             fmaxf(sacc[2][g], sacc[3][g]));
            for (int msk = 1; msk < 16; msk <<= 1)
                tm = fmaxf(tm, __shfl_xor(tm, msk));
            float mn = fmaxf(m_[g], tm);
            float alpha = __expf(m_[g] - mn);
            float ps = 0.f;
            for (int ct = 0; ct < 4; ++ct) {
                float p = __expf(sacc[ct][g] - mn);
                ps += p;
                Ps[(wave * 16 + quad * 4 + g) * 72 + ct * 16 + l15] = f2bf(p);
            }
            for (int msk = 1; msk < 16; msk <<= 1)
                ps += __shfl_xor(ps, msk);
            l_[g] = l_[g] * alpha + ps;
            m_[g] = mn;
            for (int nt = 0; nt < 8; ++nt) oacc[nt][g] *= alpha;
        }

        // PV: O += P·V (same-wave LDS RAW, in-order)
        bf16x8 pf[2];
        const short* pp = Ps + (wave * 16 + l15) * 72 + quad * 8;
        pf[0] = as_bf(*(const s16x8*)(pp));
        pf[1] = as_bf(*(const s16x8*)(pp + 32));
        for (int nt = 0; nt < 8; ++nt) {
            const short* vp = Vs + (nt * 16 + l15) * 72 + quad * 8;
            f32x4 c = oacc[nt];
            c = __builtin_amdgcn_mfma_f32_16x16x32_bf16(
                    pf[0], as_bf(*(const s16x8*)(vp)), c, 0, 0, 0);
            c = __builtin_amdgcn_mfma_f32_16x16x32_bf16(
                    pf[1], as_bf(*(const s16x8*)(vp + 32)), c, 0, 0, 0);
            oacc[nt] = c;
        }
    }

    float rl[4];
    for (int g = 0; g < 4; ++g) rl[g] = 1.f / l_[g];

    float* orow = O + ((size_t)b * SN + i0 + wave * 16 + quad * 4) * DN + l15;
    for (int nt = 0; nt < 8; ++nt)
        for (int g = 0; g < 4; ++g)
            orow[(size_t)g * DN + nt * 16] = oacc[nt][g] * rl[g];

    if (l15 == 0) {
        int rb = b * SN + i0 + wave * 16 + quad * 4;
        for (int g = 0; g < 4; ++g) {
            Mr[rb + g] = m_[g];
            Rr[rb + g] = rl[g];
        }
    }
}

// ------------------------------------------------ fixup: blob -> W (fp32)
// Writes ALL of W: lower tiles from blob via exp(s-m)*rl, upper tiles zero.
__global__ void fixup_kernel(const short* __restrict__ blob,
                             const float* __restrict__ Mr,
                             const float* __restrict__ Rr,
                             float* __restrict__ W) {
    __shared__ float Ws[64 * 68];
    const int tj = blockIdx.x, ti = blockIdx.y, b = blockIdx.z;
    const int t = threadIdx.x;
    const int i0 = ti * 64, j0 = tj * 64;
    float* wbase = W + ((size_t)b * SN + i0) * SN + j0;

    if (tj > ti) {   // strictly-upper tile: zeros only
        const f32x4 z = {0.f, 0.f, 0.f, 0.f};
        int row = t >> 2, c0 = (t & 3) * 16;
        float* wr = wbase + (size_t)row * SN + c0;
        for (int k = 0; k < 4; ++k) *(f32x4*)(wr + 4 * k) = z;
        return;
    }

    const short* bt = blob +
        ((size_t)b * 528 + (size_t)ti * (ti + 1) / 2 + tj) * 4096;
    const int wv = t >> 6, ln = t & 63;
    s16x8 a0 = *(const s16x8*)(bt + wv * 512 + ln * 8);
    s16x8 a1 = *(const s16x8*)(bt + 2048 + wv * 512 + ln * 8);
    const int rbase = wv * 16 + ((ln >> 4) << 2);
    const int cbase = ln & 15;
    for (int e = 0; e < 16; ++e) {
        short hv = (e < 8) ? a0[e] : a1[e - 8];
        int ct = e >> 2, g = e & 3;
        Ws[(rbase + g) * 68 + ct * 16 + cbase] = h2f(hv);
    }
    __syncthreads();

    int row = t >> 2, c0 = (t & 3) * 16;
    int i = i0 + row;
    float m  = Mr[b * SN + i];
    float rl = Rr[b * SN + i];
    float* wr = wbase + (size_t)row * SN + c0;
    for (int k = 0; k < 4; ++k) {
        f32x4 s4 = *(f32x4*)(Ws + row * 68 + c0 + 4 * k);
        f32x4 o;
        for (int u = 0; u < 4; ++u) {
            int j = j0 + c0 + 4 * k + u;
            o[u] = (j > i) ? 0.f : __expf(s4[u] - m) * rl;
        }
        *(f32x4*)(wr + 4 * k) = o;
    }
}

// ---------------------------------------------------------------- launch
extern "C" void kernel_launch(void* const* d_in, const int* in_sizes, int n_in,
                              void* d_out, int out_size, void* d_ws, size_t ws_size,
                              hipStream_t stream) {
    const float* Q = (const float*)d_in[0];
    const float* K = (const float*)d_in[1];
    const float* V = (const float*)d_in[2];
    float* O = (float*)d_out;
    float* W = O + (size_t)BN * SN * DN;

    short* Qb   = (short*)d_ws;
    short* Kb   = Qb + (size_t)BN * SN * DN;
    short* Vt   = Kb + (size_t)BN * SN * DN;
    short* blob = Vt + (size_t)BN * SN * DN;            // 16*528*4096 f16
    float* Mr   = (float*)(blob + (size_t)BN * 528 * 4096);
    float* Rr   = Mr + (size_t)BN * SN;

    const int n4 = (BN * SN * DN) / 4;
    cast_bf16_kernel<<<n4 / 256, 256, 0, stream>>>(Q, Qb, n4);
    cast_bf16_kernel<<<n4 / 256, 256, 0, stream>>>(K, Kb, n4);
    transpose_v_kernel<<<dim3(SN / 64, DN / 64, BN), 256, 0, stream>>>(V, Vt);
    attn_kernel<<<512, 256, 0, stream>>>(Qb, Kb, Vt, O, blob, Mr, Rr);
    fixup_kernel<<<dim3(32, 32, 16), 256, 0, stream>>>(blob, Mr, Rr, W);
}

// Round 3
// 493.842 us; speedup vs baseline: 1.0036x; 1.0036x over previous
//
#include <hip/hip_runtime.h>
#include <hip/hip_bf16.h>
#include <stdint.h>

#define BN 16
#define SN 2048
#define DN 128
#define SCALE 0.08838834764831845f   // 1/sqrt(128)

typedef float  f32x4  __attribute__((ext_vector_type(4)));
typedef short  s16x8  __attribute__((ext_vector_type(8)));
typedef short  s16x4  __attribute__((ext_vector_type(4)));
typedef __bf16 bf16x8 __attribute__((ext_vector_type(8)));

static __device__ __forceinline__ bf16x8 as_bf(s16x8 v) {
    return __builtin_bit_cast(bf16x8, v);
}
static __device__ __forceinline__ short f2bf(float f) {
    return __builtin_bit_cast(short, (__bf16)f);
}
static __device__ __forceinline__ short f2h(float f) {
    return __builtin_bit_cast(short, (_Float16)f);
}
static __device__ __forceinline__ float h2f(short s) {
    return (float)__builtin_bit_cast(_Float16, s);
}

// ---------------------------------------------------------------- prep: cast
__global__ void cast_bf16_kernel(const float* __restrict__ src,
                                 short* __restrict__ dst, int n4) {
    int idx = blockIdx.x * blockDim.x + threadIdx.x;
    if (idx >= n4) return;
    const float4 v = ((const float4*)src)[idx];
    s16x4 o;
    o[0] = f2bf(v.x); o[1] = f2bf(v.y); o[2] = f2bf(v.z); o[3] = f2bf(v.w);
    ((s16x4*)dst)[idx] = o;
}

// ------------------------------------------------- prep: V -> V^T (bf16)
__global__ void transpose_v_kernel(const float* __restrict__ V,
                                   short* __restrict__ Vt) {
    __shared__ float tile[64][65];
    const int b = blockIdx.z, j0 = blockIdx.x * 64, d0 = blockIdx.y * 64;
    const int t = threadIdx.x;
    const int r = t >> 4, c4 = (t & 15) * 4;
    const float* src = V + ((size_t)b * SN + j0) * DN + d0;
    #pragma unroll
    for (int it = 0; it < 4; ++it) {
        int rr = r + it * 16;
        const float4 v = *(const float4*)(src + (size_t)rr * DN + c4);
        tile[rr][c4 + 0] = v.x; tile[rr][c4 + 1] = v.y;
        tile[rr][c4 + 2] = v.z; tile[rr][c4 + 3] = v.w;
    }
    __syncthreads();
    short* dst = Vt + ((size_t)b * DN + d0) * SN + j0;
    #pragma unroll
    for (int it = 0; it < 4; ++it) {
        int dr = r + it * 16;
        s16x4 o;
        o[0] = f2bf(tile[c4 + 0][dr]);
        o[1] = f2bf(tile[c4 + 1][dr]);
        o[2] = f2bf(tile[c4 + 2][dr]);
        o[3] = f2bf(tile[c4 + 3][dr]);
        *(s16x4*)(dst + (size_t)dr * SN + c4) = o;
    }
}

// ------------------------------------------------------------- attention
// Single-pass flash; all register-array loops force-unrolled (a non-unrolled
// loop indexing oacc[][] lowers to scratch -> the R2 regression).
__launch_bounds__(256, 2)
__global__ void attn_kernel(const short* __restrict__ Qb,
                            const short* __restrict__ Kb,
                            const short* __restrict__ Vtb,
                            float* __restrict__ O,
                            short* __restrict__ blob,
                            float* __restrict__ Mr,
                            float* __restrict__ Rr) {
    __shared__ short Ks[64 * 136];   // K tile [j][d], pad 8
    __shared__ short Vs[128 * 72];   // V^T tile [d][j], pad 8
    __shared__ short Ps[64 * 72];    // P tile [i][j], pad 8

    const int tid  = threadIdx.x;
    const int wave = tid >> 6;
    const int lane = tid & 63;
    const int l15  = lane & 15;
    const int quad = lane >> 4;

    const int idx  = blockIdx.x;
    const int half = idx >> 8;
    const int rr_  = idx & 255;
    const int b    = ((rr_ >> 5) << 1) | half;
    const int qr   = rr_ & 31;
    const int qt   = half ? (31 - qr) : qr;
    const int i0   = qt * 64;
    const int ntiles = qt + 1;

    bf16x8 qf[4];
    {
        const short* qp = Qb + ((size_t)b * SN + (i0 + wave * 16 + l15)) * DN + quad * 8;
        #pragma unroll
        for (int ks = 0; ks < 4; ++ks)
            qf[ks] = as_bf(*(const s16x8*)(qp + ks * 32));
    }

    float m_[4], l_[4];
    #pragma unroll
    for (int g = 0; g < 4; ++g) { m_[g] = -1e30f; l_[g] = 0.f; }

    f32x4 oacc[8];
    const f32x4 zero4 = {0.f, 0.f, 0.f, 0.f};
    #pragma unroll
    for (int nt = 0; nt < 8; ++nt) oacc[nt] = zero4;

    const short* kbase = Kb  + (size_t)b * SN * DN;
    const short* vbase = Vtb + (size_t)b * DN * SN;
    const size_t tri   = (size_t)qt * (qt + 1) / 2;
    short* bbase = blob + ((size_t)b * 528 + tri) * 4096 + wave * 512 + lane * 8;

    for (int tI = 0; tI < ntiles; ++tI) {
        const int j0 = tI * 64;
        __syncthreads();
        {   // stage K tile + V^T tile
            const int row = tid >> 4, d0 = (tid & 15) * 8;
            #pragma unroll
            for (int it = 0; it < 4; ++it) {
                int rj = row + it * 16;
                *(s16x8*)(Ks + rj * 136 + d0) =
                    *(const s16x8*)(kbase + (size_t)(j0 + rj) * DN + d0);
            }
            const int dd = tid >> 3, jj0 = (tid & 7) * 8;
            #pragma unroll
            for (int it = 0; it < 4; ++it) {
                int dr = dd + it * 32;
                *(s16x8*)(Vs + dr * 72 + jj0) =
                    *(const s16x8*)(vbase + (size_t)dr * SN + j0 + jj0);
            }
        }
        __syncthreads();

        // QK^T
        f32x4 sacc[4];
        #pragma unroll
        for (int ct = 0; ct < 4; ++ct) {
            f32x4 c = {0.f, 0.f, 0.f, 0.f};
            const short* kp = Ks + (ct * 16 + l15) * 136 + quad * 8;
            #pragma unroll
            for (int ks = 0; ks < 4; ++ks)
                c = __builtin_amdgcn_mfma_f32_16x16x32_bf16(
                        qf[ks], as_bf(*(const s16x8*)(kp + ks * 32)), c, 0, 0, 0);
            sacc[ct] = c * SCALE;
        }
        if (j0 == i0) {  // straddle tile: mask j > i
            #pragma unroll
            for (int ct = 0; ct < 4; ++ct)
                #pragma unroll
                for (int g = 0; g < 4; ++g) {
                    int i = i0 + wave * 16 + quad * 4 + g;
                    int j = j0 + ct * 16 + l15;
                    if (j > i) sacc[ct][g] = -1e30f;
                }
        }

        // raw score dump: f16, register order, 2x16B coalesced stores
        {
            s16x8 h0, h1;
            #pragma unroll
            for (int e = 0; e < 8; ++e)
                h0[e] = f2h(sacc[e >> 2][e & 3]);
            #pragma unroll
            for (int e = 0; e < 8; ++e)
                h1[e] = f2h(sacc[2 + (e >> 2)][e & 3]);
            short* bt = bbase + (size_t)tI * 4096;
            *(s16x8*)(bt)        = h0;
            *(s16x8*)(bt + 2048) = h1;
        }

        // online softmax update (alpha hoisted; all loops unrolled)
        float a_[4];
        #pragma unroll
        for (int g = 0; g < 4; ++g) {
            float tm = fmaxf(fmaxf(sacc[0][g], sacc[1][g]),
                             fmaxf(sacc[2][g], sacc[3][g]));
            #pragma unroll
            for (int msk = 1; msk < 16; msk <<= 1)
                tm = fmaxf(tm, __shfl_xor(tm, msk));
            float mn = fmaxf(m_[g], tm);
            a_[g] = __expf(m_[g] - mn);
            float ps = 0.f;
            #pragma unroll
            for (int ct = 0; ct < 4; ++ct) {
                float p = __expf(sacc[ct][g] - mn);
                ps += p;
                Ps[(wave * 16 + quad * 4 + g) * 72 + ct * 16 + l15] = f2bf(p);
            }
            #pragma unroll
            for (int msk = 1; msk < 16; msk <<= 1)
                ps += __shfl_xor(ps, msk);
            l_[g] = l_[g] * a_[g] + ps;
            m_[g] = mn;
        }
        #pragma unroll
        for (int nt = 0; nt < 8; ++nt) {
            #pragma unroll
            for (int g = 0; g < 4; ++g)
                oacc[nt][g] *= a_[g];
        }

        // PV: O += P·V (same-wave LDS RAW, in-order)
        bf16x8 pf[2];
        const short* pp = Ps + (wave * 16 + l15) * 72 + quad * 8;
        pf[0] = as_bf(*(const s16x8*)(pp));
        pf[1] = as_bf(*(const s16x8*)(pp + 32));
        #pragma unroll
        for (int nt = 0; nt < 8; ++nt) {
            const short* vp = Vs + (nt * 16 + l15) * 72 + quad * 8;
            f32x4 c = oacc[nt];
            c = __builtin_amdgcn_mfma_f32_16x16x32_bf16(
                    pf[0], as_bf(*(const s16x8*)(vp)), c, 0, 0, 0);
            c = __builtin_amdgcn_mfma_f32_16x16x32_bf16(
                    pf[1], as_bf(*(const s16x8*)(vp + 32)), c, 0, 0, 0);
            oacc[nt] = c;
        }
    }

    float rl[4];
    #pragma unroll
    for (int g = 0; g < 4; ++g) rl[g] = 1.f / l_[g];

    float* orow = O + ((size_t)b * SN + i0 + wave * 16 + quad * 4) * DN + l15;
    #pragma unroll
    for (int nt = 0; nt < 8; ++nt)
        #pragma unroll
        for (int g = 0; g < 4; ++g)
            orow[(size_t)g * DN + nt * 16] = oacc[nt][g] * rl[g];

    if (l15 == 0) {
        int rb = b * SN + i0 + wave * 16 + quad * 4;
        #pragma unroll
        for (int g = 0; g < 4; ++g) {
            Mr[rb + g] = m_[g];
            Rr[rb + g] = rl[g];
        }
    }
}

// ------------------------------------------------ fixup: blob -> W (fp32)
__global__ void fixup_kernel(const short* __restrict__ blob,
                             const float* __restrict__ Mr,
                             const float* __restrict__ Rr,
                             float* __restrict__ W) {
    __shared__ float Ws[64 * 68];
    const int tj = blockIdx.x, ti = blockIdx.y, b = blockIdx.z;
    const int t = threadIdx.x;
    const int i0 = ti * 64, j0 = tj * 64;
    float* wbase = W + ((size_t)b * SN + i0) * SN + j0;

    if (tj > ti) {   // strictly-upper tile: zeros only
        const f32x4 z = {0.f, 0.f, 0.f, 0.f};
        int row = t >> 2, c0 = (t & 3) * 16;
        float* wr = wbase + (size_t)row * SN + c0;
        #pragma unroll
        for (int k = 0; k < 4; ++k) *(f32x4*)(wr + 4 * k) = z;
        return;
    }

    const short* bt = blob +
        ((size_t)b * 528 + (size_t)ti * (ti + 1) / 2 + tj) * 4096;
    const int wv = t >> 6, ln = t & 63;
    s16x8 a0 = *(const s16x8*)(bt + wv * 512 + ln * 8);
    s16x8 a1 = *(const s16x8*)(bt + 2048 + wv * 512 + ln * 8);
    const int rbase = wv * 16 + ((ln >> 4) << 2);
    const int cbase = ln & 15;
    #pragma unroll
    for (int e = 0; e < 8; ++e)
        Ws[(rbase + (e & 3)) * 68 + (e >> 2) * 16 + cbase] = h2f(a0[e]);
    #pragma unroll
    for (int e = 0; e < 8; ++e)
        Ws[(rbase + (e & 3)) * 68 + (2 + (e >> 2)) * 16 + cbase] = h2f(a1[e]);
    __syncthreads();

    int row = t >> 2, c0 = (t & 3) * 16;
    int i = i0 + row;
    float m  = Mr[b * SN + i];
    float rl = Rr[b * SN + i];
    float* wr = wbase + (size_t)row * SN + c0;
    #pragma unroll
    for (int k = 0; k < 4; ++k) {
        f32x4 s4 = *(f32x4*)(Ws + row * 68 + c0 + 4 * k);
        f32x4 o;
        #pragma unroll
        for (int u = 0; u < 4; ++u) {
            int j = j0 + c0 + 4 * k + u;
            o[u] = (j > i) ? 0.f : __expf(s4[u] - m) * rl;
        }
        *(f32x4*)(wr + 4 * k) = o;
    }
}

// ---------------------------------------------------------------- launch
extern "C" void kernel_launch(void* const* d_in, const int* in_sizes, int n_in,
                              void* d_out, int out_size, void* d_ws, size_t ws_size,
                              hipStream_t stream) {
    const float* Q = (const float*)d_in[0];
    const float* K = (const float*)d_in[1];
    const float* V = (const float*)d_in[2];
    float* O = (float*)d_out;
    float* W = O + (size_t)BN * SN * DN;

    short* Qb   = (short*)d_ws;
    short* Kb   = Qb + (size_t)BN * SN * DN;
    short* Vt   = Kb + (size_t)BN * SN * DN;
    short* blob = Vt + (size_t)BN * SN * DN;            // 16*528*4096 f16
    float* Mr   = (float*)(blob + (size_t)BN * 528 * 4096);
    float* Rr   = Mr + (size_t)BN * SN;

    const int n4 = (BN * SN * DN) / 4;
    cast_bf16_kernel<<<n4 / 256, 256, 0, stream>>>(Q, Qb, n4);
    cast_bf16_kernel<<<n4 / 256, 256, 0, stream>>>(K, Kb, n4);
    transpose_v_kernel<<<dim3(SN / 64, DN / 64, BN), 256, 0, stream>>>(V, Vt);
    attn_kernel<<<512, 256, 0, stream>>>(Qb, Kb, Vt, O, blob, Mr, Rr);
    fixup_kernel<<<dim3(32, 32, 16), 256, 0, stream>>>(blob, Mr, Rr, W);
}